// Round 1
// baseline (145.648 us; speedup 1.0000x reference)
//
#include <hip/hip_runtime.h>
#include <stdint.h>

#define BGRAPH 16
#define NPER   4096
#define NNODE  65536
#define NEDGE  262144
#define PPER   8
#define PTOT   128
#define PLEN   512
#define FDIM   64

// ---- counts[g] = #nodes with batch==g (LDS histogram to avoid atomic storms) ----
__global__ void k_counts(const int* __restrict__ batch, int* __restrict__ counts) {
    __shared__ int h[BGRAPH];
    if (threadIdx.x < BGRAPH) h[threadIdx.x] = 0;
    __syncthreads();
    int i = blockIdx.x * blockDim.x + threadIdx.x;
    if (i < NNODE) atomicAdd(&h[batch[i]], 1);
    __syncthreads();
    if (threadIdx.x < BGRAPH && h[threadIdx.x] != 0)
        atomicAdd(&counts[threadIdx.x], h[threadIdx.x]);
}

// ---- exclusive prefix sum over 16 graphs (single thread; trivial) ----
__global__ void k_scan(const int* __restrict__ counts, int* __restrict__ nstart) {
    if (blockIdx.x == 0 && threadIdx.x == 0) {
        int run = 0;
        for (int g = 0; g < BGRAPH; g++) { nstart[g] = run; run += counts[g]; }
    }
}

// ---- pathway membership bitmask: bit p of mask[n] set iff node n in pathway p ----
__global__ void k_mask(const int* __restrict__ pw, const int* __restrict__ nstart,
                       unsigned long long* __restrict__ mask) {
    int idx = blockIdx.x * blockDim.x + threadIdx.x;   // over PTOT*PLEN entries
    if (idx >= PTOT * PLEN) return;
    int p = idx / PLEN;
    int v = pw[idx];
    if (v < 0) return;                                 // padding
    int n = v + nstart[p / PPER];
    atomicOr(&mask[(size_t)n * 2 + (p >> 6)], 1ull << (p & 63));
}

// ---- node_count[n] = popcount(mask[n]) ----
__global__ void k_nodecnt(const unsigned long long* __restrict__ mask,
                          float* __restrict__ ncnt) {
    int n = blockIdx.x * blockDim.x + threadIdx.x;
    if (n >= NNODE) return;
    ncnt[n] = (float)(__popcll(mask[2 * (size_t)n]) + __popcll(mask[2 * (size_t)n + 1]));
}

// ---- compact edges with edge_count > 0; w = edge_count * edge_attr ----
__global__ void k_edges(const int* __restrict__ ei, const float* __restrict__ attr,
                        const unsigned long long* __restrict__ mask,
                        int* __restrict__ nact, int* __restrict__ sact,
                        int* __restrict__ dact, float* __restrict__ wact) {
    int e = blockIdx.x * blockDim.x + threadIdx.x;
    if (e >= NEDGE) return;
    int s = ei[e], d = ei[NEDGE + e];
    unsigned long long a0 = mask[2 * (size_t)s], a1 = mask[2 * (size_t)s + 1];
    unsigned long long b0 = mask[2 * (size_t)d], b1 = mask[2 * (size_t)d + 1];
    int c = __popcll(a0 & b0) + __popcll(a1 & b1);
    if (c > 0) {
        int idx = atomicAdd(nact, 1);
        sact[idx] = s; dact[idx] = d;
        wact[idx] = (float)c * attr[e];
    }
}

// ---- xout[n,:] = node_count[n] * xin[n,:]  (float4 vectorized) ----
__global__ void k_scale(const float4* __restrict__ xin, const float* __restrict__ ncnt,
                        float4* __restrict__ xout) {
    int idx = blockIdx.x * blockDim.x + threadIdx.x;   // NNODE * (FDIM/4)
    if (idx >= NNODE * (FDIM / 4)) return;
    int n = idx >> 4;                                  // FDIM/4 == 16 float4 per row
    float c = ncnt[n];
    float4 v = xin[idx];
    v.x *= c; v.y *= c; v.z *= c; v.w *= c;
    xout[idx] = v;
}

// ---- scatter: xout[dst,:] += xin[src,:] * w  over compacted active edges ----
__global__ void k_scatter(const float* __restrict__ xin, float* __restrict__ xout,
                          const int* __restrict__ nact, const int* __restrict__ sact,
                          const int* __restrict__ dact, const float* __restrict__ wact) {
    int lane  = threadIdx.x & 63;
    int eslot = blockIdx.x * (blockDim.x >> 6) + (threadIdx.x >> 6);
    int stride = gridDim.x * (blockDim.x >> 6);
    int na = *nact;
    for (int e = eslot; e < na; e += stride) {
        int s = sact[e], d = dact[e];
        float w = wact[e];
        atomicAdd(&xout[(size_t)d * FDIM + lane], xin[(size_t)s * FDIM + lane] * w);
    }
}

// ---- mean-pool per graph: out[g,f] = sum(x[n,f] : batch[n]==g) / counts[g] ----
__global__ void k_pool(const float* __restrict__ x, const int* __restrict__ batch,
                       const int* __restrict__ counts, float* __restrict__ out) {
    __shared__ float sm[256];
    int r0 = blockIdx.x * 256;       // 256 consecutive nodes per block (uniform graph)
    int f  = threadIdx.x & 63;
    int rs = threadIdx.x >> 6;
    float acc = 0.f;
    for (int r = rs; r < 256; r += 4)
        acc += x[(size_t)(r0 + r) * FDIM + f];
    sm[threadIdx.x] = acc;
    __syncthreads();
    if (threadIdx.x < 64) {
        float tot = sm[threadIdx.x] + sm[threadIdx.x + 64] +
                    sm[threadIdx.x + 128] + sm[threadIdx.x + 192];
        int g = batch[r0];
        atomicAdd(&out[g * FDIM + f], tot / (float)counts[g]);
    }
}

extern "C" void kernel_launch(void* const* d_in, const int* in_sizes, int n_in,
                              void* d_out, int out_size, void* d_ws, size_t ws_size,
                              hipStream_t stream) {
    const float* x     = (const float*)d_in[0];
    const int*   ei    = (const int*)d_in[1];
    const float* attr  = (const float*)d_in[2];
    const int*   pw    = (const int*)d_in[3];
    const int*   batch = (const int*)d_in[4];
    float*       out   = (float*)d_out;

    char* wsp = (char*)d_ws;
    size_t off = 0;
    auto alloc = [&](size_t bytes) {
        void* p = wsp + off;
        off = (off + bytes + 255) & ~(size_t)255;
        return p;
    };
    float* xa  = (float*)alloc(sizeof(float) * NNODE * FDIM);    // 16 MiB
    float* xb  = (float*)alloc(sizeof(float) * NNODE * FDIM);    // 16 MiB
    unsigned long long* mask = (unsigned long long*)alloc(16ull * NNODE); // 1 MiB
    float* ncnt = (float*)alloc(4ull * NNODE);                   // 256 KiB
    float* wact = (float*)alloc(4ull * NEDGE);                   // 1 MiB
    int*   sact = (int*)alloc(4ull * NEDGE);                     // 1 MiB
    int*   dact = (int*)alloc(4ull * NEDGE);                     // 1 MiB
    int*   counts = (int*)alloc(4 * BGRAPH);
    int*   nstart = (int*)alloc(4 * BGRAPH);
    int*   nact   = (int*)alloc(4);

    // ws/out are poisoned 0xAA before every launch — re-zero what needs zeros.
    hipMemsetAsync(mask,   0, 16ull * NNODE, stream);
    hipMemsetAsync(counts, 0, 4 * BGRAPH, stream);
    hipMemsetAsync(nact,   0, 4, stream);
    hipMemsetAsync(out,    0, sizeof(float) * out_size, stream);

    k_counts <<<NNODE / 256, 256, 0, stream>>>(batch, counts);
    k_scan   <<<1, 64, 0, stream>>>(counts, nstart);
    k_mask   <<<(PTOT * PLEN) / 256, 256, 0, stream>>>(pw, nstart, mask);
    k_nodecnt<<<NNODE / 256, 256, 0, stream>>>(mask, ncnt);
    k_edges  <<<NEDGE / 256, 256, 0, stream>>>(ei, attr, mask, nact, sact, dact, wact);

    // layer 1: x -> xa
    k_scale  <<<(NNODE * 16) / 256, 256, 0, stream>>>((const float4*)x, ncnt, (float4*)xa);
    k_scatter<<<512, 256, 0, stream>>>(x, xa, nact, sact, dact, wact);
    // layer 2: xa -> xb
    k_scale  <<<(NNODE * 16) / 256, 256, 0, stream>>>((const float4*)xa, ncnt, (float4*)xb);
    k_scatter<<<512, 256, 0, stream>>>(xa, xb, nact, sact, dact, wact);
    // layer 3: xb -> xa
    k_scale  <<<(NNODE * 16) / 256, 256, 0, stream>>>((const float4*)xb, ncnt, (float4*)xa);
    k_scatter<<<512, 256, 0, stream>>>(xb, xa, nact, sact, dact, wact);

    k_pool   <<<NNODE / 256, 256, 0, stream>>>(xa, batch, counts, out);
}